// Round 3
// baseline (617.903 us; speedup 1.0000x reference)
//
#include <hip/hip_runtime.h>

#define B_SZ 512
#define E_SZ 512
#define C_SZ 70722
#define NPAD 70784   /* 553*128 */
#define NTILES 553
#define EPSC 0.001f
#define MMARG 0.4f
#define HC 0.333f
#define SC 64.0f
#define PI_F 3.14159265358979323846f

typedef __attribute__((ext_vector_type(8))) short short8;
typedef __attribute__((ext_vector_type(4))) float f32x4;

__device__ __forceinline__ unsigned short f32_to_bf16(float f) {
  unsigned int u = __builtin_bit_cast(unsigned int, f);
  u += 0x7fffu + ((u >> 16) & 1u);   // RNE (inputs finite)
  return (unsigned short)(u >> 16);
}

// Fragment-linear layouts (short8 units):
//   Afrag[b>>4][k>>3][b&15]  : idx = ((b>>4)*64 + (k>>3))*16 + (b&15)
//   Bfrag[c>>4][k>>3][c&15]  : same, c over NPAD columns
// A wave's MFMA fragment (16 rows x 32 k) is then 64 consecutive short8 =
// one fully-coalesced 1KB global load: lane l reads idx base + l.

// ---------------- stats: per-row scalars (1 block, 512 threads) -------------
__global__ __launch_bounds__(512) void k_stats(
    const float* __restrict__ norms, const int* __restrict__ label,
    float* __restrict__ g_ang, float* __restrict__ g_add,
    float* __restrict__ out_cw) {
  __shared__ float sn[512];
  __shared__ int   lab[512];
  __shared__ float red[512];
  const int t = threadIdx.x;
  float x = norms[t];
  x = fminf(fmaxf(x, 0.001f), 100.0f);   // safe_norms
  sn[t] = x; lab[t] = label[t]; red[t] = x;
  __syncthreads();
  for (int s = 256; s > 0; s >>= 1) { if (t < s) red[t] += red[t + s]; __syncthreads(); }
  const float mean = red[0] * (1.0f / 512.0f);
  __syncthreads();
  const float d = x - mean;
  red[t] = d * d;
  __syncthreads();
  for (int s = 256; s > 0; s >>= 1) { if (t < s) red[t] += red[t + s]; __syncthreads(); }
  const float stdv = sqrtf(red[0] / 511.0f);     // ddof=1; T_ALPHA=1
  const float denom = stdv + EPSC;
  float cnt = 0.f, sum = 0.f;
  const int myl = lab[t];
  for (int j = 0; j < 512; ++j) { if (lab[j] == myl) { cnt += 1.0f; sum += sn[j]; } }
  const float cwm = sum / cnt;
  const float ms = fminf(fmaxf((x - mean) / denom * HC, -1.0f), 1.0f);
  out_cw[t] = fminf(fmaxf((x - cwm) / denom, -1.0f), 1.0f) * HC;
  g_ang[t] = -MMARG * ms;
  g_add[t] = MMARG + MMARG * ms;
}

// -------- emb f32 -> bf16 fragment-linear (coalesced reads) ----------------
__global__ __launch_bounds__(256) void k_convert_emb(
    const float* __restrict__ emb, unsigned short* __restrict__ Af) {
  const int g = blockIdx.x * 256 + threadIdx.x;   // 0..32767, one short8 each
  const int b  = g >> 6;                          // row
  const int kc = g & 63;                          // k-chunk
  const f32x4 a = *(const f32x4*)(emb + g * 8);
  const f32x4 c = *(const f32x4*)(emb + g * 8 + 4);
  short8 o;
  o[0] = (short)f32_to_bf16(a[0]); o[1] = (short)f32_to_bf16(a[1]);
  o[2] = (short)f32_to_bf16(a[2]); o[3] = (short)f32_to_bf16(a[3]);
  o[4] = (short)f32_to_bf16(c[0]); o[5] = (short)f32_to_bf16(c[1]);
  o[6] = (short)f32_to_bf16(c[2]); o[7] = (short)f32_to_bf16(c[3]);
  const int idx = ((b >> 4) * 64 + kc) * 16 + (b & 15);
  *((short8*)Af + idx) = o;
}

// ------- transpose+convert kernel[:,0,:] -> Bfrag + invnorm ----------------
__global__ __launch_bounds__(256) void k_prep_b(
    const float* __restrict__ Kr, unsigned short* __restrict__ Bf,
    float* __restrict__ invn) {
  __shared__ __align__(16) float Tr[64][68];   // [e][c], stride 68: 16B-aligned vec writes
  __shared__ float part[64][8];
  const int t  = threadIdx.x;
  const int c0 = blockIdx.x * 64;
  const int lr = t >> 4;        // load phase: e-row base 0..15
  const int lq = t & 15;        // load phase: float4 column index
  const int rc = t & 31;        // read phase: c base (c = rc, rc+32)
  const int ro = t >> 5;        // read phase: e-octet 0..7
  float accv[2] = {0.f, 0.f};

  for (int et = 0; et < 8; ++et) {
    const int e0 = et * 64;
#pragma unroll
    for (int i = 0; i < 4; ++i) {
      const int rr = lr + 16 * i;
      const f32x4 v = *(const f32x4*)(Kr + (size_t)(e0 + rr) * (2 * C_SZ) + c0 + lq * 4);
      *(f32x4*)(&Tr[rr][lq * 4]) = v;
    }
    __syncthreads();
#pragma unroll
    for (int i = 0; i < 2; ++i) {
      const int c  = rc + 32 * i;
      const int gc = c0 + c;
      short8 pk;
      float sq = 0.f;
#pragma unroll
      for (int j = 0; j < 8; ++j) {
        const float v = Tr[ro * 8 + j][c];
        sq += v * v;
        pk[j] = (short)f32_to_bf16(v);
      }
      accv[i] += sq;
      const int idx = ((gc >> 4) * 64 + (et * 8 + ro)) * 16 + (gc & 15);
      *((short8*)Bf + idx) = pk;
    }
    __syncthreads();
  }
  part[rc][ro]      = accv[0];
  part[rc + 32][ro] = accv[1];
  __syncthreads();
  if (t < 64) {
    float s = 0.f;
#pragma unroll
    for (int o = 0; o < 8; ++o) s += part[t][o];
    invn[c0 + t] = rsqrtf(s);
  }
}

// ---------------- cos2_tgt[b]: one wave per row ----------------------------
__global__ __launch_bounds__(64) void k_cos2(
    const float* __restrict__ emb, const float* __restrict__ Kr,
    const int* __restrict__ label, float* __restrict__ cos2t) {
  const int b = blockIdx.x;
  const int l = threadIdx.x;
  const int lb = label[b];
  float s1 = 0.f, s2 = 0.f;
#pragma unroll
  for (int e = l; e < E_SZ; e += 64) {
    const float a  = emb[b * E_SZ + e];
    const float kv = Kr[(size_t)e * (2 * C_SZ) + C_SZ + lb];
    s1 += a * kv;
    s2 += kv * kv;
  }
#pragma unroll
  for (int off = 32; off > 0; off >>= 1) {
    s1 += __shfl_down(s1, off);
    s2 += __shfl_down(s2, off);
  }
  if (l == 0) {
    float cv = s1 * rsqrtf(s2);
    cv = fminf(fmaxf(cv, -1.0f + EPSC), 1.0f - EPSC);
    cos2t[b] = cv;
  }
}

// ---------------- main MFMA GEMM + fused epilogue --------------------------
// v4: barrier-free fragment-direct GEMM. No LDS tiles; A/B fragments loaded
// straight from global (L2/L3-resident) via fragment-linear layout: each
// fragment = one coalesced 1KB global_load_dwordx4 per wave. 256 threads,
// 4 waves as 2x2 of 64x64 tiles, acc[4][4]. Zero __syncthreads in k-loop.
__global__ __launch_bounds__(256, 4) void k_gemm(
    const unsigned short* __restrict__ Af, const unsigned short* __restrict__ Bf,
    const float* __restrict__ invn, const int* __restrict__ label,
    const float* __restrict__ g_ang, const float* __restrict__ g_add,
    const float* __restrict__ cos2t,
    float* __restrict__ out0, float* __restrict__ out1, float* __restrict__ tgtv1) {
  __shared__ int   lab_s[128];
  __shared__ float ga_s[128];
  __shared__ float gd_s[128];
  __shared__ float c2_s[128];
  __shared__ float inv_s[128];

  const int tid = threadIdx.x;
  // bijective XCD-chunked swizzle (m204): 4 m-tiles of one B-panel -> same XCD L2
  const int nwg = 4 * NTILES;                 // 2212
  const int q = nwg >> 3, r = nwg & 7;        // 276, 4
  const int xcd = blockIdx.x & 7, pos = blockIdx.x >> 3;
  const int logical = (xcd < r ? xcd * (q + 1) : r * (q + 1) + (xcd - r) * q) + pos;
  const int m0 = (logical & 3) * 128;
  const int n0 = (logical >> 2) * 128;

  if (tid < 128) {
    lab_s[tid] = label[m0 + tid];
    ga_s[tid]  = g_ang[m0 + tid];
    gd_s[tid]  = g_add[m0 + tid];
    c2_s[tid]  = cos2t[m0 + tid];
    inv_s[tid] = invn[n0 + tid];
  }
  __syncthreads();   // once; k-loop below is barrier-free

  const int l  = tid & 63;
  const int w  = tid >> 6;          // 0..3
  const int wm = (w >> 1) * 64;
  const int wn = (w & 1) * 64;

  // lane base pointers into fragment-linear buffers (see layout note above)
  const short8* __restrict__ pA =
      (const short8*)Af + (size_t)((m0 + wm) >> 4) * 1024 + l;
  const short8* __restrict__ pB =
      (const short8*)Bf + (size_t)((n0 + wn) >> 4) * 1024 + l;

  f32x4 acc[4][4];
#pragma unroll
  for (int i = 0; i < 4; ++i)
#pragma unroll
    for (int j = 0; j < 4; ++j) acc[i][j] = (f32x4){0.f, 0.f, 0.f, 0.f};

#pragma unroll 1
  for (int kt = 0; kt < 16; ++kt) {
    short8 af[4], bf[4];
    const int ko = kt * 64;         // 4 k-chunks * 16 lanes per k-step
#pragma unroll
    for (int mi = 0; mi < 4; ++mi) af[mi] = pA[mi * 1024 + ko];
#pragma unroll
    for (int ni = 0; ni < 4; ++ni) bf[ni] = pB[ni * 1024 + ko];
#pragma unroll
    for (int mi = 0; mi < 4; ++mi)
#pragma unroll
      for (int ni = 0; ni < 4; ++ni)
        acc[mi][ni] = __builtin_amdgcn_mfma_f32_16x16x32_bf16(af[mi], bf[ni], acc[mi][ni], 0, 0, 0);
  }

  // epilogue: C/D layout col = lane&15, row = (lane>>4)*4 + reg
  const int lr  = l & 15;
  const int lq4 = (l >> 4) * 4;
#pragma unroll
  for (int mi = 0; mi < 4; ++mi) {
    const int blb = wm + mi * 16 + lq4;
#pragma unroll
    for (int ni = 0; ni < 4; ++ni) {
      const int cl = wn + ni * 16 + lr;
      const int c  = n0 + cl;
      if (c < C_SZ) {
        const float inv = inv_s[cl];
        const f32x4 a = acc[mi][ni];
#pragma unroll
        for (int rg = 0; rg < 4; ++rg) {
          const int bl = blb + rg;
          const int b  = m0 + bl;
          float w1 = a[rg] * inv;
          w1 = fminf(fmaxf(w1, -1.0f + EPSC), 1.0f - EPSC);
          float v0 = w1 * SC;   // non-target: cos(acos(w1)) == w1
          float v1 = v0;
          if (c == lab_s[bl]) {                 // rare: one column per row
            const float ga = ga_s[bl];
            const float gd = gd_s[bl];
            float th = acosf(w1) + ga;
            th = fminf(fmaxf(th, EPSC), PI_F - EPSC);
            v0 = (cosf(th) - gd) * SC;
            const float w2 = c2_s[bl];
            float th2 = acosf(w2) + ga;
            th2 = fminf(fmaxf(th2, EPSC), PI_F - EPSC);
            v1 = (cosf(th2) - gd) * SC;
            if (tgtv1) tgtv1[b] = v1;
          }
          const size_t off = (size_t)b * C_SZ + c;
          out0[off] = v0;
          if (out1) out1[off] = v1;
        }
      }
    }
  }
}

// ---------------- fallback: out1 = out0 with targets patched ---------------
__global__ __launch_bounds__(256) void k_patch(
    const float* __restrict__ out0, const int* __restrict__ label,
    const float* __restrict__ tgtv1, float* __restrict__ out1) {
  const int b = blockIdx.y;
  const int i2 = (blockIdx.x * 256 + threadIdx.x) * 2;
  if (i2 >= C_SZ) return;
  const size_t off = (size_t)b * C_SZ + i2;
  float2 v = *(const float2*)(out0 + off);
  const int lb = label[b];
  if (lb == i2)          v.x = tgtv1[b];
  else if (lb == i2 + 1) v.y = tgtv1[b];
  *(float2*)(out1 + off) = v;
}

extern "C" void kernel_launch(void* const* d_in, const int* in_sizes, int n_in,
                              void* d_out, int out_size, void* d_ws, size_t ws_size,
                              hipStream_t stream) {
  const float* emb   = (const float*)d_in[0];
  const float* norms = (const float*)d_in[1];
  const int*   label = (const int*)d_in[2];
  const float* Kr    = (const float*)d_in[3];

  float* out  = (float*)d_out;
  float* out0 = out;
  float* out1 = out + (size_t)B_SZ * C_SZ;
  float* outcw = out + (size_t)2 * B_SZ * C_SZ;

  char* ws = (char*)d_ws;
  unsigned short* Af = (unsigned short*)(ws);           // 524288 B
  float* invn  = (float*)(ws + 524288);                 // NPAD*4 = 283136 B
  float* g_ang = (float*)(ws + 807424);
  float* g_add = (float*)(ws + 809472);
  float* c2    = (float*)(ws + 811520);
  float* tgtv1 = (float*)(ws + 813568);
  const size_t bt_off = 1048576;
  const size_t need_direct = bt_off + (size_t)NPAD * E_SZ * 2;  // 73.5 MB
  const bool direct = ws_size >= need_direct;
  unsigned short* Bf = direct
      ? (unsigned short*)(ws + bt_off)
      : (unsigned short*)((char*)d_out + (size_t)B_SZ * C_SZ * 4);  // out1 region

  k_stats<<<1, 512, 0, stream>>>(norms, label, g_ang, g_add, outcw);
  k_convert_emb<<<(B_SZ * E_SZ) / (256 * 8), 256, 0, stream>>>(emb, Af);
  k_prep_b<<<NPAD / 64, 256, 0, stream>>>(Kr, Bf, invn);
  k_cos2<<<B_SZ, 64, 0, stream>>>(emb, Kr, label, c2);
  k_gemm<<<dim3(4 * NTILES), 256, 0, stream>>>(Af, Bf, invn, label, g_ang, g_add, c2,
                                               out0, direct ? out1 : (float*)nullptr,
                                               direct ? (float*)nullptr : tgtv1);
  if (!direct) {
    k_patch<<<dim3((C_SZ / 2 + 255) / 256, B_SZ), 256, 0, stream>>>(out0, label, tgtv1, out1);
  }
}